// Round 1
// baseline (329.480 us; speedup 1.0000x reference)
//
#include <hip/hip_runtime.h>
#include <hip/hip_bf16.h>
#include <stdint.h>

#define N_ROWS 8192
#define DIM    512
#define TILE   128
#define BK     64

typedef __attribute__((ext_vector_type(4))) float f32x4;
typedef __attribute__((ext_vector_type(8))) short bf16x8;

// RNE float -> bf16 bits (no NaN inputs here)
__device__ __forceinline__ unsigned short f2bf(float f) {
    unsigned int u = __float_as_uint(f);
    unsigned int r = (u + 0x7FFFu + ((u >> 16) & 1u)) >> 16;
    return (unsigned short)r;
}

// async global -> LDS, 16 bytes per lane (wave-uniform base + lane*16 dest)
__device__ __forceinline__ void gload_lds16(const void* g, void* l) {
    __builtin_amdgcn_global_load_lds(
        (const __attribute__((address_space(1))) unsigned int*)g,
        (__attribute__((address_space(3))) unsigned int*)l,
        16, 0, 0);
}

// ---------------- Kernel 1: L2-normalize rows + cast to bf16 ----------------
// one wave per row; 8192 rows of z1 then 8192 rows of z2 (16384 waves total)
__global__ __launch_bounds__(256) void norm_cast_kernel(
    const float* __restrict__ z1, const float* __restrict__ z2,
    unsigned short* __restrict__ o1, unsigned short* __restrict__ o2)
{
    int row  = blockIdx.x * 4 + (threadIdx.x >> 6);
    int lane = threadIdx.x & 63;
    const float* src;
    unsigned short* dst;
    if (row < N_ROWS) { src = z1 + (size_t)row * DIM;            dst = o1 + (size_t)row * DIM; }
    else              { src = z2 + (size_t)(row - N_ROWS) * DIM; dst = o2 + (size_t)(row - N_ROWS) * DIM; }

    const float4* s4 = (const float4*)src + lane * 2;
    float4 a = s4[0], b = s4[1];
    float ss = a.x*a.x + a.y*a.y + a.z*a.z + a.w*a.w
             + b.x*b.x + b.y*b.y + b.z*b.z + b.w*b.w;
#pragma unroll
    for (int x = 1; x < 64; x <<= 1) ss += __shfl_xor(ss, x);
    float inv = 1.0f / fmaxf(sqrtf(ss), 1e-12f);

    uint4 outv;
    outv.x = (unsigned)f2bf(a.x*inv) | ((unsigned)f2bf(a.y*inv) << 16);
    outv.y = (unsigned)f2bf(a.z*inv) | ((unsigned)f2bf(a.w*inv) << 16);
    outv.z = (unsigned)f2bf(b.x*inv) | ((unsigned)f2bf(b.y*inv) << 16);
    outv.w = (unsigned)f2bf(b.z*inv) | ((unsigned)f2bf(b.w*inv) << 16);
    *((uint4*)(dst + lane * 8)) = outv;
}

// ---------------- Kernel 2: fused sim GEMM + per-row softmax stats ----------
// C[i][j] = z1n[i]·z2n[j]; per row accumulate:
//   den   += exp(sim-10)
//   smask += exp(sim-10)            where ids[i]==ids[j]
//   ssq   += exp(sim-10)^2          where ids[i]!=ids[j]
__global__ __launch_bounds__(256) void fused_sim_kernel(
    const unsigned short* __restrict__ A,   // z1n bf16 bits [8192][512]
    const unsigned short* __restrict__ B,   // z2n bf16 bits [8192][512]
    const int* __restrict__ ids,
    float* __restrict__ den_g, float* __restrict__ sm_g, float* __restrict__ sq_g)
{
    __shared__ unsigned short As[TILE * BK];   // 16 KB, linear [row][k] row-major
    __shared__ unsigned short Bs[TILE * BK];   // 16 KB
    __shared__ int idr[TILE];
    __shared__ int idc[TILE];

    const int tid  = threadIdx.x;
    const int lane = tid & 63;
    const int wid  = tid >> 6;
    const int wr   = wid >> 1, wc = wid & 1;   // 2x2 waves, 64x64 each
    const int brow = blockIdx.y * TILE;
    const int bcol = blockIdx.x * TILE;

    if (tid < TILE)      idr[tid]        = ids[brow + tid];
    else                 idc[tid - TILE] = ids[bcol + (tid - TILE)];

    f32x4 acc[4][4];
#pragma unroll
    for (int m = 0; m < 4; ++m)
#pragma unroll
        for (int n = 0; n < 4; ++n) acc[m][n] = (f32x4)0.f;

    for (int kk = 0; kk < DIM / BK; ++kk) {
        const int k0 = kk * BK;
        // stage A and B tiles: 128 rows x 64 k, 16 KB each, 4 issues x 256 thr x 16B
#pragma unroll
        for (int it = 0; it < 4; ++it) {
            int seg = it * 256 + tid;          // 0..1023, 16B segments
            int r   = seg >> 3;                // 0..127
            int c8  = seg & 7;                 // 0..7
            gload_lds16(A + (size_t)(brow + r) * DIM + k0 + c8 * 8, &As[seg * 8]);
            gload_lds16(B + (size_t)(bcol + r) * DIM + k0 + c8 * 8, &Bs[seg * 8]);
        }
        __syncthreads();

#pragma unroll
        for (int ks = 0; ks < 2; ++ks) {
            bf16x8 af[4], bfr[4];
#pragma unroll
            for (int m = 0; m < 4; ++m) {
                int rowa = wr * 64 + m * 16 + (lane & 15);
                af[m] = *(const bf16x8*)&As[rowa * BK + ks * 32 + (lane >> 4) * 8];
            }
#pragma unroll
            for (int n = 0; n < 4; ++n) {
                int rowb = wc * 64 + n * 16 + (lane & 15);
                bfr[n] = *(const bf16x8*)&Bs[rowb * BK + ks * 32 + (lane >> 4) * 8];
            }
#pragma unroll
            for (int m = 0; m < 4; ++m)
#pragma unroll
                for (int n = 0; n < 4; ++n)
                    acc[m][n] = __builtin_amdgcn_mfma_f32_16x16x32_bf16(af[m], bfr[n], acc[m][n], 0, 0, 0);
        }
        __syncthreads();
    }

    // epilogue: C/D layout col=lane&15, row=(lane>>4)*4+reg  [guide §3, m89-verified]
    const int colg = lane & 15;
    const int rg   = lane >> 4;
#pragma unroll
    for (int m = 0; m < 4; ++m) {
#pragma unroll
        for (int r = 0; r < 4; ++r) {
            int lrow = wr * 64 + m * 16 + rg * 4 + r;
            int rid  = idr[lrow];
            float dp = 0.f, sp = 0.f, qp = 0.f;
#pragma unroll
            for (int n = 0; n < 4; ++n) {
                int lcol = wc * 64 + n * 16 + colg;
                float v  = acc[m][n][r];
                float e  = __expf(v * 10.0f - 10.0f);   // exp(sim - 10), sim = v/tau
                bool msk = (rid == idc[lcol]);
                dp += e;
                sp += msk ? e : 0.f;
                qp += msk ? 0.f : e * e;
            }
            // butterfly over the 16 lanes holding different columns of this row
#pragma unroll
            for (int x = 1; x < 16; x <<= 1) {
                dp += __shfl_xor(dp, x);
                sp += __shfl_xor(sp, x);
                qp += __shfl_xor(qp, x);
            }
            if (colg == 0) {
                atomicAdd(&den_g[brow + lrow], dp);
                atomicAdd(&sm_g[brow + lrow], sp);
                atomicAdd(&sq_g[brow + lrow], qp);
            }
        }
    }
}

// ---------------- Kernel 3: per-row loss + mean ----------------
__global__ __launch_bounds__(256) void finalize_kernel(
    const float* __restrict__ den_g, const float* __restrict__ sm_g,
    const float* __restrict__ sq_g, float* __restrict__ out)
{
    int tid = threadIdx.x;
    float acc = 0.f;
    for (int i = tid; i < N_ROWS; i += 256) {
        float d   = den_g[i];
        float num = sm_g[i] + sq_g[i] / d;
        acc += -logf(num / (d + 1e-8f) + 1e-8f);
    }
#pragma unroll
    for (int x = 1; x < 64; x <<= 1) acc += __shfl_xor(acc, x);
    __shared__ float part[4];
    if ((tid & 63) == 0) part[tid >> 6] = acc;
    __syncthreads();
    if (tid == 0) out[0] = (part[0] + part[1] + part[2] + part[3]) * (1.0f / (float)N_ROWS);
}

extern "C" void kernel_launch(void* const* d_in, const int* in_sizes, int n_in,
                              void* d_out, int out_size, void* d_ws, size_t ws_size,
                              hipStream_t stream) {
    const float* z1  = (const float*)d_in[0];
    const float* z2  = (const float*)d_in[1];
    const int*   ids = (const int*)d_in[2];

    char* ws = (char*)d_ws;
    unsigned short* z1n = (unsigned short*)ws;                                   // 8 MB
    unsigned short* z2n = (unsigned short*)(ws + (size_t)N_ROWS * DIM * 2);      // 8 MB
    float* den = (float*)(ws + (size_t)N_ROWS * DIM * 4);                        // 32 KB
    float* sm  = den + N_ROWS;
    float* sq  = den + 2 * N_ROWS;

    hipMemsetAsync(den, 0, 3 * N_ROWS * sizeof(float), stream);
    norm_cast_kernel<<<dim3(4096), dim3(256), 0, stream>>>(z1, z2, z1n, z2n);
    fused_sim_kernel<<<dim3(64, 64), dim3(256), 0, stream>>>(z1n, z2n, ids, den, sm, sq);
    finalize_kernel<<<1, 256, 0, stream>>>(den, sm, sq, (float*)d_out);
}

// Round 2
// 154.488 us; speedup vs baseline: 2.1327x; 2.1327x over previous
//
#include <hip/hip_runtime.h>
#include <hip/hip_bf16.h>
#include <stdint.h>

#define N_ROWS 8192
#define DIM    512
#define TILE   128
#define BK     64
#define NCB    64      // column blocks (8192 / TILE)
#define NKK    (DIM / BK)

typedef __attribute__((ext_vector_type(4))) float f32x4;
typedef __attribute__((ext_vector_type(8))) short bf16x8;

// RNE float -> bf16 bits (no NaN inputs here)
__device__ __forceinline__ unsigned short f2bf(float f) {
    unsigned int u = __float_as_uint(f);
    unsigned int r = (u + 0x7FFFu + ((u >> 16) & 1u)) >> 16;
    return (unsigned short)r;
}

// async global -> LDS, 16 bytes per lane (wave-uniform base + lane*16 dest)
__device__ __forceinline__ void gload_lds16(const void* g, void* l) {
    __builtin_amdgcn_global_load_lds(
        (const __attribute__((address_space(1))) unsigned int*)g,
        (__attribute__((address_space(3))) unsigned int*)l,
        16, 0, 0);
}

// ---------------- Kernel 1: L2-normalize rows + cast to bf16 ----------------
__global__ __launch_bounds__(256) void norm_cast_kernel(
    const float* __restrict__ z1, const float* __restrict__ z2,
    unsigned short* __restrict__ o1, unsigned short* __restrict__ o2)
{
    int row  = blockIdx.x * 4 + (threadIdx.x >> 6);
    int lane = threadIdx.x & 63;
    const float* src;
    unsigned short* dst;
    if (row < N_ROWS) { src = z1 + (size_t)row * DIM;            dst = o1 + (size_t)row * DIM; }
    else              { src = z2 + (size_t)(row - N_ROWS) * DIM; dst = o2 + (size_t)(row - N_ROWS) * DIM; }

    const float4* s4 = (const float4*)src + lane * 2;
    float4 a = s4[0], b = s4[1];
    float ss = a.x*a.x + a.y*a.y + a.z*a.z + a.w*a.w
             + b.x*b.x + b.y*b.y + b.z*b.z + b.w*b.w;
#pragma unroll
    for (int x = 1; x < 64; x <<= 1) ss += __shfl_xor(ss, x);
    float inv = 1.0f / fmaxf(sqrtf(ss), 1e-12f);

    uint4 outv;
    outv.x = (unsigned)f2bf(a.x*inv) | ((unsigned)f2bf(a.y*inv) << 16);
    outv.y = (unsigned)f2bf(a.z*inv) | ((unsigned)f2bf(a.w*inv) << 16);
    outv.z = (unsigned)f2bf(b.x*inv) | ((unsigned)f2bf(b.y*inv) << 16);
    outv.w = (unsigned)f2bf(b.z*inv) | ((unsigned)f2bf(b.w*inv) << 16);
    *((uint4*)(dst + lane * 8)) = outv;
}

// ---------------- Kernel 2: fused sim GEMM + per-row softmax stats ----------
// Per row i over this block's 128 columns j:
//   den += e, sm += e (ids match), sq += e^2 (ids differ),  e = exp(sim-10)
// Partials written per column-block (no atomics): partial[s][cb][row].
__global__ __launch_bounds__(256) void fused_sim_kernel(
    const unsigned short* __restrict__ A,   // z1n bf16 bits [8192][512]
    const unsigned short* __restrict__ B,   // z2n bf16 bits [8192][512]
    const int* __restrict__ ids,
    float* __restrict__ partial)            // [3][NCB][N_ROWS]
{
    __shared__ unsigned short As[2][TILE * BK];   // 2 x 16 KB
    __shared__ unsigned short Bs[2][TILE * BK];   // 2 x 16 KB
    __shared__ int idr[TILE];
    __shared__ int idc[TILE];
    __shared__ float red[2][3][TILE];             // per-wc partial sums

    const int tid  = threadIdx.x;
    const int lane = tid & 63;
    const int wid  = tid >> 6;
    const int wr   = wid >> 1, wc = wid & 1;      // 2x2 waves, 64x64 each

    // XCD-aware swizzle: 4096 blocks, 512 contiguous virt blocks per XCD
    const int flat = blockIdx.y * 64 + blockIdx.x;
    const int virt = (flat & 7) * 512 + (flat >> 3);
    const int by = virt >> 6, bx = virt & 63;
    const int brow = by * TILE;
    const int bcol = bx * TILE;

    if (tid < TILE)      idr[tid]        = ids[brow + tid];
    else                 idc[tid - TILE] = ids[bcol + (tid - TILE)];

    // stage one BK-tile of A and B into buffer `buf`, with pre-swizzled
    // global source so that LDS[seg = r*8+c8] holds global (r, c8 ^ (r&7)).
    auto stage = [&](int buf, int k0) {
#pragma unroll
        for (int it = 0; it < 4; ++it) {
            int seg = it * 256 + tid;          // 0..1023 (16B segments)
            int r   = seg >> 3;                // 0..127
            int c8  = seg & 7;                 // 0..7 (8-elem groups)
            int c8g = c8 ^ (r & 7);            // swizzled source column group
            gload_lds16(A + (size_t)(brow + r) * DIM + k0 + c8g * 8, &As[buf][seg * 8]);
            gload_lds16(B + (size_t)(bcol + r) * DIM + k0 + c8g * 8, &Bs[buf][seg * 8]);
        }
    };

    f32x4 acc[4][4];
#pragma unroll
    for (int m = 0; m < 4; ++m)
#pragma unroll
        for (int n = 0; n < 4; ++n) acc[m][n] = (f32x4)0.f;

    stage(0, 0);
    __syncthreads();                            // emits vmcnt(0) drain + barrier

#pragma unroll
    for (int kk = 0; kk < NKK; ++kk) {
        const int cur = kk & 1;
        if (kk < NKK - 1) stage(cur ^ 1, (kk + 1) * BK);   // prefetch next tile

#pragma unroll
        for (int ks = 0; ks < 2; ++ks) {
            bf16x8 af[4], bfr[4];
#pragma unroll
            for (int m = 0; m < 4; ++m) {
                int rowa = wr * 64 + m * 16 + (lane & 15);
                int c8u  = ks * 4 + (lane >> 4);
                int c8s  = c8u ^ (rowa & 7);               // read-side XOR swizzle
                af[m] = *(const bf16x8*)&As[cur][rowa * BK + c8s * 8];
            }
#pragma unroll
            for (int n = 0; n < 4; ++n) {
                int rowb = wc * 64 + n * 16 + (lane & 15);
                int c8u  = ks * 4 + (lane >> 4);
                int c8s  = c8u ^ (rowb & 7);
                bfr[n] = *(const bf16x8*)&Bs[cur][rowb * BK + c8s * 8];
            }
#pragma unroll
            for (int m = 0; m < 4; ++m)
#pragma unroll
                for (int n = 0; n < 4; ++n)
                    acc[m][n] = __builtin_amdgcn_mfma_f32_16x16x32_bf16(af[m], bfr[n], acc[m][n], 0, 0, 0);
        }
        __syncthreads();                        // drains prefetch + lds reads
    }

    // epilogue: C/D layout col=lane&15, row=(lane>>4)*4+reg
    const int colg = lane & 15;
    const int rg   = lane >> 4;
#pragma unroll
    for (int m = 0; m < 4; ++m) {
#pragma unroll
        for (int r = 0; r < 4; ++r) {
            int lrow = wr * 64 + m * 16 + rg * 4 + r;
            int rid  = idr[lrow];
            float dp = 0.f, sp = 0.f, qp = 0.f;
#pragma unroll
            for (int n = 0; n < 4; ++n) {
                int lcol = wc * 64 + n * 16 + colg;
                float v  = acc[m][n][r];
                float e  = __expf(v * 10.0f - 10.0f);   // exp(sim - 10)
                bool msk = (rid == idc[lcol]);
                dp += e;
                sp += msk ? e : 0.f;
                qp += msk ? 0.f : e * e;
            }
#pragma unroll
            for (int x = 1; x < 16; x <<= 1) {
                dp += __shfl_xor(dp, x);
                sp += __shfl_xor(sp, x);
                qp += __shfl_xor(qp, x);
            }
            if (colg == 0) {                    // lanes 0,16,32,48 (rg=0..3)
                red[wc][0][lrow] = dp;          // unique (wc,row) -> plain store
                red[wc][1][lrow] = sp;
                red[wc][2][lrow] = qp;
            }
        }
    }
    __syncthreads();
    if (tid < TILE) {
#pragma unroll
        for (int s = 0; s < 3; ++s) {
            float v = red[0][s][tid] + red[1][s][tid];
            partial[((size_t)s * NCB + bx) * N_ROWS + brow + tid] = v;
        }
    }
}

// ---------------- Kernel 3: per-row loss, per-block sums ----------------
__global__ __launch_bounds__(256) void reduce_kernel(
    const float* __restrict__ partial, float* __restrict__ blocksum)
{
    int row = blockIdx.x * 256 + threadIdx.x;
    float den = 0.f, sm = 0.f, sq = 0.f;
#pragma unroll 4
    for (int cb = 0; cb < NCB; ++cb) {
        den += partial[((size_t)0 * NCB + cb) * N_ROWS + row];
        sm  += partial[((size_t)1 * NCB + cb) * N_ROWS + row];
        sq  += partial[((size_t)2 * NCB + cb) * N_ROWS + row];
    }
    float num  = sm + sq / den;
    float loss = -logf(num / (den + 1e-8f) + 1e-8f);
#pragma unroll
    for (int x = 1; x < 64; x <<= 1) loss += __shfl_xor(loss, x);
    __shared__ float p[4];
    if ((threadIdx.x & 63) == 0) p[threadIdx.x >> 6] = loss;
    __syncthreads();
    if (threadIdx.x == 0) blocksum[blockIdx.x] = p[0] + p[1] + p[2] + p[3];
}

__global__ void final_kernel(const float* __restrict__ blocksum, float* __restrict__ out)
{
    float v = (threadIdx.x < 32) ? blocksum[threadIdx.x] : 0.f;
#pragma unroll
    for (int x = 1; x < 64; x <<= 1) v += __shfl_xor(v, x);
    if (threadIdx.x == 0) out[0] = v * (1.0f / (float)N_ROWS);
}

extern "C" void kernel_launch(void* const* d_in, const int* in_sizes, int n_in,
                              void* d_out, int out_size, void* d_ws, size_t ws_size,
                              hipStream_t stream) {
    const float* z1  = (const float*)d_in[0];
    const float* z2  = (const float*)d_in[1];
    const int*   ids = (const int*)d_in[2];

    char* ws = (char*)d_ws;
    unsigned short* z1n = (unsigned short*)ws;                                   // 8 MB
    unsigned short* z2n = (unsigned short*)(ws + (size_t)N_ROWS * DIM * 2);      // 8 MB
    float* partial  = (float*)(ws + (size_t)N_ROWS * DIM * 4);                   // 6.29 MB
    float* blocksum = partial + (size_t)3 * NCB * N_ROWS;                        // 128 B

    norm_cast_kernel<<<dim3(4096), dim3(256), 0, stream>>>(z1, z2, z1n, z2n);
    fused_sim_kernel<<<dim3(64, 64), dim3(256), 0, stream>>>(z1n, z2n, ids, partial);
    reduce_kernel<<<dim3(32), dim3(256), 0, stream>>>(partial, blocksum);
    final_kernel<<<dim3(1), dim3(64), 0, stream>>>(blocksum, (float*)d_out);
}

// Round 3
// 125.708 us; speedup vs baseline: 2.6210x; 1.2289x over previous
//
#include <hip/hip_runtime.h>
#include <hip/hip_bf16.h>
#include <stdint.h>

#define N_ROWS  8192
#define DIM     512
#define BM      256                 // tile M = N = 256
#define BK      32                  // K-step
#define NT      (DIM / BK)          // 16 K-tiles
#define NBUF    4                   // LDS ring buffers (4 K-tiles)
#define TSZ     (BM * BK)           // elements per tile buffer
#define NCB     32                  // column blocks (8192/256)
#define THREADS 512

typedef __attribute__((ext_vector_type(4))) float f32x4;
typedef __attribute__((ext_vector_type(8))) short bf16x8;

#define BAR()    { asm volatile("" ::: "memory"); __builtin_amdgcn_s_barrier(); asm volatile("" ::: "memory"); }
#define WAITV(n) asm volatile("s_waitcnt vmcnt(" #n ")" ::: "memory")
#define WAITL0() asm volatile("s_waitcnt lgkmcnt(0)" ::: "memory")

// RNE float -> bf16 bits
__device__ __forceinline__ unsigned short f2bf(float f) {
    unsigned int u = __float_as_uint(f);
    unsigned int r = (u + 0x7FFFu + ((u >> 16) & 1u)) >> 16;
    return (unsigned short)r;
}

// async global -> LDS, 16 B per lane (wave-uniform LDS base + lane*16)
__device__ __forceinline__ void gload_lds16(const void* g, void* l) {
    __builtin_amdgcn_global_load_lds(
        (const __attribute__((address_space(1))) unsigned int*)g,
        (__attribute__((address_space(3))) unsigned int*)l,
        16, 0, 0);
}

// ---------------- Kernel 1: L2-normalize rows + cast to bf16 ----------------
__global__ __launch_bounds__(256) void norm_cast_kernel(
    const float* __restrict__ z1, const float* __restrict__ z2,
    unsigned short* __restrict__ o1, unsigned short* __restrict__ o2)
{
    int row  = blockIdx.x * 4 + (threadIdx.x >> 6);
    int lane = threadIdx.x & 63;
    const float* src;
    unsigned short* dst;
    if (row < N_ROWS) { src = z1 + (size_t)row * DIM;            dst = o1 + (size_t)row * DIM; }
    else              { src = z2 + (size_t)(row - N_ROWS) * DIM; dst = o2 + (size_t)(row - N_ROWS) * DIM; }

    const float4* s4 = (const float4*)src + lane * 2;
    float4 a = s4[0], b = s4[1];
    float ss = a.x*a.x + a.y*a.y + a.z*a.z + a.w*a.w
             + b.x*b.x + b.y*b.y + b.z*b.z + b.w*b.w;
#pragma unroll
    for (int x = 1; x < 64; x <<= 1) ss += __shfl_xor(ss, x);
    float inv = 1.0f / fmaxf(sqrtf(ss), 1e-12f);

    uint4 outv;
    outv.x = (unsigned)f2bf(a.x*inv) | ((unsigned)f2bf(a.y*inv) << 16);
    outv.y = (unsigned)f2bf(a.z*inv) | ((unsigned)f2bf(a.w*inv) << 16);
    outv.z = (unsigned)f2bf(b.x*inv) | ((unsigned)f2bf(b.y*inv) << 16);
    outv.w = (unsigned)f2bf(b.z*inv) | ((unsigned)f2bf(b.w*inv) << 16);
    *((uint4*)(dst + lane * 8)) = outv;
}

// ---------------- Kernel 2: fused 256x256 8-phase-style sim GEMM ------------
// Per row i over this block's 256 cols j: den += e, sm += e (ids equal),
// sq += e^2 (ids differ), e = exp(sim-10). Partials per column-block.
__global__ __launch_bounds__(THREADS, 2) void fused_sim_kernel(
    const unsigned short* __restrict__ A,   // z1n bf16 bits [8192][512]
    const unsigned short* __restrict__ B,   // z2n bf16 bits [8192][512]
    const int* __restrict__ ids,
    float* __restrict__ partial)            // [3][NCB][N_ROWS]
{
    __shared__ unsigned short As[NBUF][TSZ];   // 64 KB
    __shared__ unsigned short Bs[NBUF][TSZ];   // 64 KB
    __shared__ int   idr[BM], idc[BM];         // 2 KB
    __shared__ float red[4][3][BM];            // 12 KB

    const int tid  = threadIdx.x;
    const int lane = tid & 63;
    const int wid  = tid >> 6;
    const int wr   = wid >> 2;                 // 0..1  (M half: 128 rows)
    const int wc   = wid & 3;                  // 0..3  (N quarter: 64 cols)

    // 2D XCD chunking: each XCD owns a 4-wide bx stripe; by sweeps inside.
    const int flat = blockIdx.x;
    const int xcd  = flat & 7;
    const int sidx = flat >> 3;                // 0..127
    const int bx   = xcd * 4 + (sidx & 3);     // 0..31
    const int by   = sidx >> 2;                // 0..31
    const int brow = by * BM;
    const int bcol = bx * BM;

    if (tid < BM)           idr[tid]        = ids[brow + tid];
    else if (tid < 2 * BM)  idc[tid - BM]   = ids[bcol + (tid - BM)];

    // staging geometry: thread -> (row-in-half sr = tid>>2, slot sc8 = tid&3)
    // LDS slot (row, c8) holds global column-group c8 ^ ((row>>1)&3)
    const int sr  = tid >> 2;                  // 0..127
    const int sc8 = tid & 3;                   // 0..3
    const int scg = sc8 ^ ((sr >> 1) & 3);     // pre-swizzled source group

    auto stageA = [&](int buf, int k0) {
#pragma unroll
        for (int h = 0; h < 2; ++h) {
            int row = h * 128 + sr;
            gload_lds16(A + (size_t)(brow + row) * DIM + k0 + scg * 8,
                        &As[buf][row * BK + sc8 * 8]);
        }
    };
    auto stageB = [&](int buf, int k0) {
#pragma unroll
        for (int h = 0; h < 2; ++h) {
            int row = h * 128 + sr;
            gload_lds16(B + (size_t)(bcol + row) * DIM + k0 + scg * 8,
                        &Bs[buf][row * BK + sc8 * 8]);
        }
    };

    const int fr = lane & 15;                  // fragment row-in-16 / C col
    const int fc = lane >> 4;                  // fragment k-group / C row grp

    auto ldA = [&](int buf, int m) -> bf16x8 {
        int row = wr * 128 + m * 16 + fr;
        int cs  = fc ^ ((row >> 1) & 3);
        return *(const bf16x8*)&As[buf][row * BK + cs * 8];
    };
    auto ldB = [&](int buf, int n) -> bf16x8 {
        int row = wc * 64 + n * 16 + fr;
        int cs  = fc ^ ((row >> 1) & 3);
        return *(const bf16x8*)&Bs[buf][row * BK + cs * 8];
    };

    f32x4 acc[8][4];
#pragma unroll
    for (int m = 0; m < 8; ++m)
#pragma unroll
        for (int n = 0; n < 4; ++n) acc[m][n] = (f32x4)0.f;

    // prologue: stage tiles 0 and 1 (4 loads each)
    stageA(0, 0);      stageB(0, 0);
    stageA(1, BK);     stageB(1, BK);
    WAITL0();                       // idr/idc visible to all waves after BAR
    WAITV(4);                       // tile 0 landed (tile 1's 4 in flight)
    BAR();

    for (int t = 0; t < NT; ++t) {
        const int cur = t & 3;
        const int nb  = (t + 2) & 3;
        const int k2  = (t + 2) * BK;
        const bool st = (t + 2 < NT);

        // ---- phase A: m0-3 x n0-3 ----
        bf16x8 a0 = ldA(cur, 0), a1 = ldA(cur, 1), a2 = ldA(cur, 2), a3 = ldA(cur, 3);
        bf16x8 b0 = ldB(cur, 0), b1 = ldB(cur, 1), b2 = ldB(cur, 2), b3 = ldB(cur, 3);
        if (st) stageA(nb, k2);     // 2 loads into ring slot t+2
        BAR();
        __builtin_amdgcn_s_setprio(1);
        acc[0][0] = __builtin_amdgcn_mfma_f32_16x16x32_bf16(a0, b0, acc[0][0], 0, 0, 0);
        acc[0][1] = __builtin_amdgcn_mfma_f32_16x16x32_bf16(a0, b1, acc[0][1], 0, 0, 0);
        acc[0][2] = __builtin_amdgcn_mfma_f32_16x16x32_bf16(a0, b2, acc[0][2], 0, 0, 0);
        acc[0][3] = __builtin_amdgcn_mfma_f32_16x16x32_bf16(a0, b3, acc[0][3], 0, 0, 0);
        acc[1][0] = __builtin_amdgcn_mfma_f32_16x16x32_bf16(a1, b0, acc[1][0], 0, 0, 0);
        acc[1][1] = __builtin_amdgcn_mfma_f32_16x16x32_bf16(a1, b1, acc[1][1], 0, 0, 0);
        acc[1][2] = __builtin_amdgcn_mfma_f32_16x16x32_bf16(a1, b2, acc[1][2], 0, 0, 0);
        acc[1][3] = __builtin_amdgcn_mfma_f32_16x16x32_bf16(a1, b3, acc[1][3], 0, 0, 0);
        acc[2][0] = __builtin_amdgcn_mfma_f32_16x16x32_bf16(a2, b0, acc[2][0], 0, 0, 0);
        acc[2][1] = __builtin_amdgcn_mfma_f32_16x16x32_bf16(a2, b1, acc[2][1], 0, 0, 0);
        acc[2][2] = __builtin_amdgcn_mfma_f32_16x16x32_bf16(a2, b2, acc[2][2], 0, 0, 0);
        acc[2][3] = __builtin_amdgcn_mfma_f32_16x16x32_bf16(a2, b3, acc[2][3], 0, 0, 0);
        acc[3][0] = __builtin_amdgcn_mfma_f32_16x16x32_bf16(a3, b0, acc[3][0], 0, 0, 0);
        acc[3][1] = __builtin_amdgcn_mfma_f32_16x16x32_bf16(a3, b1, acc[3][1], 0, 0, 0);
        acc[3][2] = __builtin_amdgcn_mfma_f32_16x16x32_bf16(a3, b2, acc[3][2], 0, 0, 0);
        acc[3][3] = __builtin_amdgcn_mfma_f32_16x16x32_bf16(a3, b3, acc[3][3], 0, 0, 0);
        __builtin_amdgcn_s_setprio(0);
        BAR();

        // ---- phase B: m4-7 x n0-3 (B frags reused in registers) ----
        bf16x8 a4 = ldA(cur, 4), a5 = ldA(cur, 5), a6 = ldA(cur, 6), a7 = ldA(cur, 7);
        if (st) stageB(nb, k2);     // 2 loads
        BAR();
        __builtin_amdgcn_s_setprio(1);
        acc[4][0] = __builtin_amdgcn_mfma_f32_16x16x32_bf16(a4, b0, acc[4][0], 0, 0, 0);
        acc[4][1] = __builtin_amdgcn_mfma_f32_16x16x32_bf16(a4, b1, acc[4][1], 0, 0, 0);
        acc[4][2] = __builtin_amdgcn_mfma_f32_16x16x32_bf16(a4, b2, acc[4][2], 0, 0, 0);
        acc[4][3] = __builtin_amdgcn_mfma_f32_16x16x32_bf16(a4, b3, acc[4][3], 0, 0, 0);
        acc[5][0] = __builtin_amdgcn_mfma_f32_16x16x32_bf16(a5, b0, acc[5][0], 0, 0, 0);
        acc[5][1] = __builtin_amdgcn_mfma_f32_16x16x32_bf16(a5, b1, acc[5][1], 0, 0, 0);
        acc[5][2] = __builtin_amdgcn_mfma_f32_16x16x32_bf16(a5, b2, acc[5][2], 0, 0, 0);
        acc[5][3] = __builtin_amdgcn_mfma_f32_16x16x32_bf16(a5, b3, acc[5][3], 0, 0, 0);
        acc[6][0] = __builtin_amdgcn_mfma_f32_16x16x32_bf16(a6, b0, acc[6][0], 0, 0, 0);
        acc[6][1] = __builtin_amdgcn_mfma_f32_16x16x32_bf16(a6, b1, acc[6][1], 0, 0, 0);
        acc[6][2] = __builtin_amdgcn_mfma_f32_16x16x32_bf16(a6, b2, acc[6][2], 0, 0, 0);
        acc[6][3] = __builtin_amdgcn_mfma_f32_16x16x32_bf16(a6, b3, acc[6][3], 0, 0, 0);
        acc[7][0] = __builtin_amdgcn_mfma_f32_16x16x32_bf16(a7, b0, acc[7][0], 0, 0, 0);
        acc[7][1] = __builtin_amdgcn_mfma_f32_16x16x32_bf16(a7, b1, acc[7][1], 0, 0, 0);
        acc[7][2] = __builtin_amdgcn_mfma_f32_16x16x32_bf16(a7, b2, acc[7][2], 0, 0, 0);
        acc[7][3] = __builtin_amdgcn_mfma_f32_16x16x32_bf16(a7, b3, acc[7][3], 0, 0, 0);
        __builtin_amdgcn_s_setprio(0);
        // counted tile-boundary wait: drain tile t+1's loads, keep t+2's 4 in flight
        if (t < NT - 2) { WAITV(4); } else { WAITV(0); }
        BAR();
    }

    // ---- epilogue: exp/mask/row-reduce; C/D col=lane&15, row=(lane>>4)*4+r
    const int colg = fr;
    const int rg   = fc;
#pragma unroll
    for (int m = 0; m < 8; ++m) {
#pragma unroll
        for (int r = 0; r < 4; ++r) {
            int lrow = wr * 128 + m * 16 + rg * 4 + r;
            int rid  = idr[lrow];
            float dp = 0.f, sp = 0.f, qp = 0.f;
#pragma unroll
            for (int n = 0; n < 4; ++n) {
                int lcol = wc * 64 + n * 16 + colg;
                float v  = acc[m][n][r];
                float e  = __expf(v * 10.0f - 10.0f);   // exp(sim - 10)
                bool msk = (rid == idc[lcol]);
                dp += e;
                sp += msk ? e : 0.f;
                qp += msk ? 0.f : e * e;
            }
#pragma unroll
            for (int x = 1; x < 16; x <<= 1) {
                dp += __shfl_xor(dp, x);
                sp += __shfl_xor(sp, x);
                qp += __shfl_xor(qp, x);
            }
            if (colg == 0) {                    // lanes rg*16: unique (wc,row)
                red[wc][0][lrow] = dp;
                red[wc][1][lrow] = sp;
                red[wc][2][lrow] = qp;
            }
        }
    }
    __syncthreads();
    if (tid < BM) {
#pragma unroll
        for (int s = 0; s < 3; ++s) {
            float v = red[0][s][tid] + red[1][s][tid] + red[2][s][tid] + red[3][s][tid];
            partial[((size_t)s * NCB + bx) * N_ROWS + brow + tid] = v;
        }
    }
}

// ---------------- Kernel 3: per-row loss, per-block sums ----------------
__global__ __launch_bounds__(256) void reduce_kernel(
    const float* __restrict__ partial, float* __restrict__ blocksum)
{
    int row = blockIdx.x * 256 + threadIdx.x;
    float den = 0.f, sm = 0.f, sq = 0.f;
#pragma unroll 4
    for (int cb = 0; cb < NCB; ++cb) {
        den += partial[((size_t)0 * NCB + cb) * N_ROWS + row];
        sm  += partial[((size_t)1 * NCB + cb) * N_ROWS + row];
        sq  += partial[((size_t)2 * NCB + cb) * N_ROWS + row];
    }
    float num  = sm + sq / den;
    float loss = -logf(num / (den + 1e-8f) + 1e-8f);
#pragma unroll
    for (int x = 1; x < 64; x <<= 1) loss += __shfl_xor(loss, x);
    __shared__ float p[4];
    if ((threadIdx.x & 63) == 0) p[threadIdx.x >> 6] = loss;
    __syncthreads();
    if (threadIdx.x == 0) blocksum[blockIdx.x] = p[0] + p[1] + p[2] + p[3];
}

__global__ void final_kernel(const float* __restrict__ blocksum, float* __restrict__ out)
{
    float v = (threadIdx.x < 32) ? blocksum[threadIdx.x] : 0.f;
#pragma unroll
    for (int x = 1; x < 64; x <<= 1) v += __shfl_xor(v, x);
    if (threadIdx.x == 0) out[0] = v * (1.0f / (float)N_ROWS);
}

extern "C" void kernel_launch(void* const* d_in, const int* in_sizes, int n_in,
                              void* d_out, int out_size, void* d_ws, size_t ws_size,
                              hipStream_t stream) {
    const float* z1  = (const float*)d_in[0];
    const float* z2  = (const float*)d_in[1];
    const int*   ids = (const int*)d_in[2];

    char* ws = (char*)d_ws;
    unsigned short* z1n = (unsigned short*)ws;                                   // 8 MB
    unsigned short* z2n = (unsigned short*)(ws + (size_t)N_ROWS * DIM * 2);      // 8 MB
    float* partial  = (float*)(ws + (size_t)N_ROWS * DIM * 4);                   // 3 MB
    float* blocksum = partial + (size_t)3 * NCB * N_ROWS;                        // 128 B

    norm_cast_kernel<<<dim3(4096), dim3(256), 0, stream>>>(z1, z2, z1n, z2n);
    fused_sim_kernel<<<dim3(1024), dim3(THREADS), 0, stream>>>(z1n, z2n, ids, partial);
    reduce_kernel<<<dim3(32), dim3(256), 0, stream>>>(partial, blocksum);
    final_kernel<<<dim3(1), dim3(64), 0, stream>>>(blocksum, (float*)d_out);
}

// Round 4
// 105.484 us; speedup vs baseline: 3.1235x; 1.1917x over previous
//
#include <hip/hip_runtime.h>
#include <hip/hip_bf16.h>
#include <stdint.h>

#define N_ROWS  8192
#define DIM     512
#define BM      256                 // tile M = N = 256
#define BK      32                  // K-step
#define NT      (DIM / BK)          // 16 K-tiles
#define NBUF    4                   // LDS ring buffers (4 K-tiles)
#define TSZ     (BM * BK)           // elements per tile buffer
#define NCB     32                  // column blocks (8192/256)
#define THREADS 512

typedef __attribute__((ext_vector_type(4))) float f32x4;
typedef __attribute__((ext_vector_type(8))) short bf16x8;

#define BAR()    { asm volatile("" ::: "memory"); __builtin_amdgcn_s_barrier(); asm volatile("" ::: "memory"); }
#define WAITV(n) asm volatile("s_waitcnt vmcnt(" #n ")" ::: "memory")
#define WAITL0() asm volatile("s_waitcnt lgkmcnt(0)" ::: "memory")

// RNE float -> bf16 bits
__device__ __forceinline__ unsigned short f2bf(float f) {
    unsigned int u = __float_as_uint(f);
    unsigned int r = (u + 0x7FFFu + ((u >> 16) & 1u)) >> 16;
    return (unsigned short)r;
}

// async global -> LDS, 16 B per lane (wave-uniform LDS base + lane*16)
__device__ __forceinline__ void gload_lds16(const void* g, void* l) {
    __builtin_amdgcn_global_load_lds(
        (const __attribute__((address_space(1))) unsigned int*)g,
        (__attribute__((address_space(3))) unsigned int*)l,
        16, 0, 0);
}

// ---------------- Kernel 1: L2-normalize rows + cast to bf16 ----------------
__global__ __launch_bounds__(256) void norm_cast_kernel(
    const float* __restrict__ z1, const float* __restrict__ z2,
    unsigned short* __restrict__ o1, unsigned short* __restrict__ o2)
{
    int row  = blockIdx.x * 4 + (threadIdx.x >> 6);
    int lane = threadIdx.x & 63;
    const float* src;
    unsigned short* dst;
    if (row < N_ROWS) { src = z1 + (size_t)row * DIM;            dst = o1 + (size_t)row * DIM; }
    else              { src = z2 + (size_t)(row - N_ROWS) * DIM; dst = o2 + (size_t)(row - N_ROWS) * DIM; }

    const float4* s4 = (const float4*)src + lane * 2;
    float4 a = s4[0], b = s4[1];
    float ss = a.x*a.x + a.y*a.y + a.z*a.z + a.w*a.w
             + b.x*b.x + b.y*b.y + b.z*b.z + b.w*b.w;
#pragma unroll
    for (int x = 1; x < 64; x <<= 1) ss += __shfl_xor(ss, x);
    float inv = 1.0f / fmaxf(sqrtf(ss), 1e-12f);

    uint4 outv;
    outv.x = (unsigned)f2bf(a.x*inv) | ((unsigned)f2bf(a.y*inv) << 16);
    outv.y = (unsigned)f2bf(a.z*inv) | ((unsigned)f2bf(a.w*inv) << 16);
    outv.z = (unsigned)f2bf(b.x*inv) | ((unsigned)f2bf(b.y*inv) << 16);
    outv.w = (unsigned)f2bf(b.z*inv) | ((unsigned)f2bf(b.w*inv) << 16);
    *((uint4*)(dst + lane * 8)) = outv;
}

// ---------------- Kernel 2: fused 256x256 sim GEMM, swapped operands -------
// acc[mj][ni] = mfma(Bfrag, Afrag): output ROW axis = j (z2 row, reduction
// axis, register-indexed), COL axis = i (z1 row, lane-fixed). Per-lane
// den/sm/sq accumulate in registers over 32 j's; cross-lane = 2-hop butterfly.
__global__ __launch_bounds__(THREADS, 2) void fused_sim_kernel(
    const unsigned short* __restrict__ A,   // z1n bf16 bits [8192][512]
    const unsigned short* __restrict__ B,   // z2n bf16 bits [8192][512]
    const int* __restrict__ ids,
    float* __restrict__ partial)            // [3][NCB][N_ROWS]
{
    __shared__ unsigned short As[NBUF][TSZ];   // 64 KB
    __shared__ unsigned short Bs[NBUF][TSZ];   // 64 KB
    __shared__ int   idr[BM], idc[BM];         // 2 KB
    __shared__ float red[2][3][BM];            // 6 KB

    const int tid  = threadIdx.x;
    const int lane = tid & 63;
    const int wid  = tid >> 6;
    const int wr   = wid >> 2;                 // 0..1  (j half: 128 B-rows)
    const int wc   = wid & 3;                  // 0..3  (i quarter: 64 A-rows)

    // 2D XCD chunking: each XCD owns a 4-wide bx stripe; by sweeps inside.
    const int flat = blockIdx.x;
    const int xcd  = flat & 7;
    const int sidx = flat >> 3;                // 0..127
    const int bx   = xcd * 4 + (sidx & 3);     // 0..31  (j block)
    const int by   = sidx >> 2;                // 0..31  (i block)
    const int brow = by * BM;
    const int bcol = bx * BM;

    if (tid < BM)           idr[tid]        = ids[brow + tid];
    else if (tid < 2 * BM)  idc[tid - BM]   = ids[bcol + (tid - BM)];

    // staging geometry: thread -> (row-in-half sr = tid>>2, slot sc8 = tid&3)
    // LDS slot (row, c8) holds global column-group c8 ^ ((row>>1)&3)
    const int sr  = tid >> 2;                  // 0..127
    const int sc8 = tid & 3;                   // 0..3
    const int scg = sc8 ^ ((sr >> 1) & 3);     // pre-swizzled source group

    auto stageA = [&](int buf, int k0) {
#pragma unroll
        for (int h = 0; h < 2; ++h) {
            int row = h * 128 + sr;
            gload_lds16(A + (size_t)(brow + row) * DIM + k0 + scg * 8,
                        &As[buf][row * BK + sc8 * 8]);
        }
    };
    auto stageB = [&](int buf, int k0) {
#pragma unroll
        for (int h = 0; h < 2; ++h) {
            int row = h * 128 + sr;
            gload_lds16(B + (size_t)(bcol + row) * DIM + k0 + scg * 8,
                        &Bs[buf][row * BK + sc8 * 8]);
        }
    };

    const int fr = lane & 15;                  // frag row-in-16 / D col (i)
    const int fc = lane >> 4;                  // frag k-group / D row grp (j)

    auto ldB = [&](int buf, int m) -> bf16x8 { // 8 frags: wave's 128 j-rows
        int row = wr * 128 + m * 16 + fr;
        int cs  = fc ^ ((row >> 1) & 3);
        return *(const bf16x8*)&Bs[buf][row * BK + cs * 8];
    };
    auto ldA = [&](int buf, int n) -> bf16x8 { // 4 frags: wave's 64 i-rows
        int row = wc * 64 + n * 16 + fr;
        int cs  = fc ^ ((row >> 1) & 3);
        return *(const bf16x8*)&As[buf][row * BK + cs * 8];
    };

    f32x4 acc[8][4];
#pragma unroll
    for (int m = 0; m < 8; ++m)
#pragma unroll
        for (int n = 0; n < 4; ++n) acc[m][n] = (f32x4)0.f;

    // prologue: stage tiles 0 and 1 (4 loads each)
    stageA(0, 0);      stageB(0, 0);
    stageA(1, BK);     stageB(1, BK);
    WAITL0();                       // idr/idc visible to all waves after BAR
    WAITV(4);                       // tile 0 landed (tile 1's 4 in flight)
    BAR();

    for (int t = 0; t < NT; ++t) {
        const int cur = t & 3;
        const int nb  = (t + 2) & 3;
        const int k2  = (t + 2) * BK;
        const bool st = (t + 2 < NT);

        // ---- phase A: j-frags 0-3 x i-frags 0-3 ----
        bf16x8 b0 = ldB(cur, 0), b1 = ldB(cur, 1), b2 = ldB(cur, 2), b3 = ldB(cur, 3);
        bf16x8 a0 = ldA(cur, 0), a1 = ldA(cur, 1), a2 = ldA(cur, 2), a3 = ldA(cur, 3);
        if (st) stageA(nb, k2);     // 2 loads into ring slot t+2
        BAR();
        __builtin_amdgcn_s_setprio(1);
        acc[0][0] = __builtin_amdgcn_mfma_f32_16x16x32_bf16(b0, a0, acc[0][0], 0, 0, 0);
        acc[0][1] = __builtin_amdgcn_mfma_f32_16x16x32_bf16(b0, a1, acc[0][1], 0, 0, 0);
        acc[0][2] = __builtin_amdgcn_mfma_f32_16x16x32_bf16(b0, a2, acc[0][2], 0, 0, 0);
        acc[0][3] = __builtin_amdgcn_mfma_f32_16x16x32_bf16(b0, a3, acc[0][3], 0, 0, 0);
        acc[1][0] = __builtin_amdgcn_mfma_f32_16x16x32_bf16(b1, a0, acc[1][0], 0, 0, 0);
        acc[1][1] = __builtin_amdgcn_mfma_f32_16x16x32_bf16(b1, a1, acc[1][1], 0, 0, 0);
        acc[1][2] = __builtin_amdgcn_mfma_f32_16x16x32_bf16(b1, a2, acc[1][2], 0, 0, 0);
        acc[1][3] = __builtin_amdgcn_mfma_f32_16x16x32_bf16(b1, a3, acc[1][3], 0, 0, 0);
        acc[2][0] = __builtin_amdgcn_mfma_f32_16x16x32_bf16(b2, a0, acc[2][0], 0, 0, 0);
        acc[2][1] = __builtin_amdgcn_mfma_f32_16x16x32_bf16(b2, a1, acc[2][1], 0, 0, 0);
        acc[2][2] = __builtin_amdgcn_mfma_f32_16x16x32_bf16(b2, a2, acc[2][2], 0, 0, 0);
        acc[2][3] = __builtin_amdgcn_mfma_f32_16x16x32_bf16(b2, a3, acc[2][3], 0, 0, 0);
        acc[3][0] = __builtin_amdgcn_mfma_f32_16x16x32_bf16(b3, a0, acc[3][0], 0, 0, 0);
        acc[3][1] = __builtin_amdgcn_mfma_f32_16x16x32_bf16(b3, a1, acc[3][1], 0, 0, 0);
        acc[3][2] = __builtin_amdgcn_mfma_f32_16x16x32_bf16(b3, a2, acc[3][2], 0, 0, 0);
        acc[3][3] = __builtin_amdgcn_mfma_f32_16x16x32_bf16(b3, a3, acc[3][3], 0, 0, 0);
        __builtin_amdgcn_s_setprio(0);
        BAR();

        // ---- phase B: j-frags 4-7 x i-frags 0-3 (A frags reused in regs) ----
        bf16x8 b4 = ldB(cur, 4), b5 = ldB(cur, 5), b6 = ldB(cur, 6), b7 = ldB(cur, 7);
        if (st) stageB(nb, k2);     // 2 loads
        BAR();
        __builtin_amdgcn_s_setprio(1);
        acc[4][0] = __builtin_amdgcn_mfma_f32_16x16x32_bf16(b4, a0, acc[4][0], 0, 0, 0);
        acc[4][1] = __builtin_amdgcn_mfma_f32_16x16x32_bf16(b4, a1, acc[4][1], 0, 0, 0);
        acc[4][2] = __builtin_amdgcn_mfma_f32_16x16x32_bf16(b4, a2, acc[4][2], 0, 0, 0);
        acc[4][3] = __builtin_amdgcn_mfma_f32_16x16x32_bf16(b4, a3, acc[4][3], 0, 0, 0);
        acc[5][0] = __builtin_amdgcn_mfma_f32_16x16x32_bf16(b5, a0, acc[5][0], 0, 0, 0);
        acc[5][1] = __builtin_amdgcn_mfma_f32_16x16x32_bf16(b5, a1, acc[5][1], 0, 0, 0);
        acc[5][2] = __builtin_amdgcn_mfma_f32_16x16x32_bf16(b5, a2, acc[5][2], 0, 0, 0);
        acc[5][3] = __builtin_amdgcn_mfma_f32_16x16x32_bf16(b5, a3, acc[5][3], 0, 0, 0);
        acc[6][0] = __builtin_amdgcn_mfma_f32_16x16x32_bf16(b6, a0, acc[6][0], 0, 0, 0);
        acc[6][1] = __builtin_amdgcn_mfma_f32_16x16x32_bf16(b6, a1, acc[6][1], 0, 0, 0);
        acc[6][2] = __builtin_amdgcn_mfma_f32_16x16x32_bf16(b6, a2, acc[6][2], 0, 0, 0);
        acc[6][3] = __builtin_amdgcn_mfma_f32_16x16x32_bf16(b6, a3, acc[6][3], 0, 0, 0);
        acc[7][0] = __builtin_amdgcn_mfma_f32_16x16x32_bf16(b7, a0, acc[7][0], 0, 0, 0);
        acc[7][1] = __builtin_amdgcn_mfma_f32_16x16x32_bf16(b7, a1, acc[7][1], 0, 0, 0);
        acc[7][2] = __builtin_amdgcn_mfma_f32_16x16x32_bf16(b7, a2, acc[7][2], 0, 0, 0);
        acc[7][3] = __builtin_amdgcn_mfma_f32_16x16x32_bf16(b7, a3, acc[7][3], 0, 0, 0);
        __builtin_amdgcn_s_setprio(0);
        // counted tile-boundary wait: drain tile t+1's loads, keep t+2's 4 in flight
        if (t < NT - 2) { WAITV(4); } else { WAITV(0); }
        BAR();
    }

    // ---- epilogue: per-lane register accumulation over j, 2-hop butterfly
    // D layout: col (i) = lane&15 fixed; row (j) = fc*4 + reg within 16-block.
    const int rg = fc;
    int   rid[4];
    float dp[4], sp[4], qp[4];
#pragma unroll
    for (int ni = 0; ni < 4; ++ni) {
        rid[ni] = idr[wc * 64 + ni * 16 + fr];
        dp[ni] = 0.f; sp[ni] = 0.f; qp[ni] = 0.f;
    }
#pragma unroll
    for (int mj = 0; mj < 8; ++mj) {
#pragma unroll
        for (int r = 0; r < 4; ++r) {
            int j   = wr * 128 + mj * 16 + rg * 4 + r;
            int cid = idc[j];                       // broadcast within rg group
#pragma unroll
            for (int ni = 0; ni < 4; ++ni) {
                float v = acc[mj][ni][r];
                float e = __expf(v * 10.0f - 10.0f);    // exp(sim - 10)
                bool msk = (rid[ni] == cid);
                dp[ni] += e;
                sp[ni] += msk ? e : 0.f;
                qp[ni] += msk ? 0.f : e * e;
            }
        }
    }
#pragma unroll
    for (int ni = 0; ni < 4; ++ni) {
#pragma unroll
        for (int x = 16; x < 64; x <<= 1) {
            dp[ni] += __shfl_xor(dp[ni], x);
            sp[ni] += __shfl_xor(sp[ni], x);
            qp[ni] += __shfl_xor(qp[ni], x);
        }
    }
    // lane (rg, fr) stores ni = rg's values (static select, no runtime index)
    {
        float dv = (rg == 0) ? dp[0] : (rg == 1) ? dp[1] : (rg == 2) ? dp[2] : dp[3];
        float sv = (rg == 0) ? sp[0] : (rg == 1) ? sp[1] : (rg == 2) ? sp[2] : sp[3];
        float qv = (rg == 0) ? qp[0] : (rg == 1) ? qp[1] : (rg == 2) ? qp[2] : qp[3];
        int i = wc * 64 + rg * 16 + fr;
        red[wr][0][i] = dv;
        red[wr][1][i] = sv;
        red[wr][2][i] = qv;
    }
    __syncthreads();
    if (tid < BM) {
#pragma unroll
        for (int s = 0; s < 3; ++s) {
            float v = red[0][s][tid] + red[1][s][tid];
            partial[((size_t)s * NCB + bx) * N_ROWS + brow + tid] = v;
        }
    }
}

// ---------------- Kernel 3: per-row loss, per-block sums ----------------
__global__ __launch_bounds__(256) void reduce_kernel(
    const float* __restrict__ partial, float* __restrict__ blocksum)
{
    int row = blockIdx.x * 256 + threadIdx.x;
    float den = 0.f, sm = 0.f, sq = 0.f;
#pragma unroll 4
    for (int cb = 0; cb < NCB; ++cb) {
        den += partial[((size_t)0 * NCB + cb) * N_ROWS + row];
        sm  += partial[((size_t)1 * NCB + cb) * N_ROWS + row];
        sq  += partial[((size_t)2 * NCB + cb) * N_ROWS + row];
    }
    float num  = sm + sq / den;
    float loss = -logf(num / (den + 1e-8f) + 1e-8f);
#pragma unroll
    for (int x = 1; x < 64; x <<= 1) loss += __shfl_xor(loss, x);
    __shared__ float p[4];
    if ((threadIdx.x & 63) == 0) p[threadIdx.x >> 6] = loss;
    __syncthreads();
    if (threadIdx.x == 0) blocksum[blockIdx.x] = p[0] + p[1] + p[2] + p[3];
}

__global__ void final_kernel(const float* __restrict__ blocksum, float* __restrict__ out)
{
    float v = (threadIdx.x < 32) ? blocksum[threadIdx.x] : 0.f;
#pragma unroll
    for (int x = 1; x < 64; x <<= 1) v += __shfl_xor(v, x);
    if (threadIdx.x == 0) out[0] = v * (1.0f / (float)N_ROWS);
}

extern "C" void kernel_launch(void* const* d_in, const int* in_sizes, int n_in,
                              void* d_out, int out_size, void* d_ws, size_t ws_size,
                              hipStream_t stream) {
    const float* z1  = (const float*)d_in[0];
    const float* z2  = (const float*)d_in[1];
    const int*   ids = (const int*)d_in[2];

    char* ws = (char*)d_ws;
    unsigned short* z1n = (unsigned short*)ws;                                   // 8 MB
    unsigned short* z2n = (unsigned short*)(ws + (size_t)N_ROWS * DIM * 2);      // 8 MB
    float* partial  = (float*)(ws + (size_t)N_ROWS * DIM * 4);                   // 3 MB
    float* blocksum = partial + (size_t)3 * NCB * N_ROWS;                        // 128 B

    norm_cast_kernel<<<dim3(4096), dim3(256), 0, stream>>>(z1, z2, z1n, z2n);
    fused_sim_kernel<<<dim3(1024), dim3(THREADS), 0, stream>>>(z1n, z2n, ids, partial);
    reduce_kernel<<<dim3(32), dim3(256), 0, stream>>>(partial, blocksum);
    final_kernel<<<dim3(1), dim3(64), 0, stream>>>(blocksum, (float*)d_out);
}

// Round 5
// 100.099 us; speedup vs baseline: 3.2915x; 1.0538x over previous
//
#include <hip/hip_runtime.h>
#include <hip/hip_bf16.h>
#include <stdint.h>

#define N_ROWS  8192
#define DIM     512
#define BM      256                 // tile M = N = 256
#define BK      32                  // K-step
#define NT      (DIM / BK)          // 16 K-tiles
#define NBUF    4                   // LDS ring buffers (4 K-tiles)
#define TSZ     (BM * BK)           // elements per tile buffer
#define NCB     32                  // column blocks (8192/256)
#define THREADS 512

typedef __attribute__((ext_vector_type(4))) float f32x4;
typedef __attribute__((ext_vector_type(8))) short bf16x8;

#define BAR()    { asm volatile("" ::: "memory"); __builtin_amdgcn_s_barrier(); asm volatile("" ::: "memory"); }
#define WAITV(n) asm volatile("s_waitcnt vmcnt(" #n ")" ::: "memory")
#define WAITL0() asm volatile("s_waitcnt lgkmcnt(0)" ::: "memory")

// RNE float -> bf16 bits
__device__ __forceinline__ unsigned short f2bf(float f) {
    unsigned int u = __float_as_uint(f);
    unsigned int r = (u + 0x7FFFu + ((u >> 16) & 1u)) >> 16;
    return (unsigned short)r;
}

// async global -> LDS, 16 B per lane (wave-uniform LDS base + lane*16)
__device__ __forceinline__ void gload_lds16(const void* g, void* l) {
    __builtin_amdgcn_global_load_lds(
        (const __attribute__((address_space(1))) unsigned int*)g,
        (__attribute__((address_space(3))) unsigned int*)l,
        16, 0, 0);
}

// ---------------- Kernel 1: L2-normalize rows + cast to bf16 ----------------
__global__ __launch_bounds__(256) void norm_cast_kernel(
    const float* __restrict__ z1, const float* __restrict__ z2,
    unsigned short* __restrict__ o1, unsigned short* __restrict__ o2)
{
    int row  = blockIdx.x * 4 + (threadIdx.x >> 6);
    int lane = threadIdx.x & 63;
    const float* src;
    unsigned short* dst;
    if (row < N_ROWS) { src = z1 + (size_t)row * DIM;            dst = o1 + (size_t)row * DIM; }
    else              { src = z2 + (size_t)(row - N_ROWS) * DIM; dst = o2 + (size_t)(row - N_ROWS) * DIM; }

    const float4* s4 = (const float4*)src + lane * 2;
    float4 a = s4[0], b = s4[1];
    float ss = a.x*a.x + a.y*a.y + a.z*a.z + a.w*a.w
             + b.x*b.x + b.y*b.y + b.z*b.z + b.w*b.w;
#pragma unroll
    for (int x = 1; x < 64; x <<= 1) ss += __shfl_xor(ss, x);
    float inv = 1.0f / fmaxf(sqrtf(ss), 1e-12f);

    uint4 outv;
    outv.x = (unsigned)f2bf(a.x*inv) | ((unsigned)f2bf(a.y*inv) << 16);
    outv.y = (unsigned)f2bf(a.z*inv) | ((unsigned)f2bf(a.w*inv) << 16);
    outv.z = (unsigned)f2bf(b.x*inv) | ((unsigned)f2bf(b.y*inv) << 16);
    outv.w = (unsigned)f2bf(b.z*inv) | ((unsigned)f2bf(b.w*inv) << 16);
    *((uint4*)(dst + lane * 8)) = outv;
}

// ---------------- Kernel 2: fused 256x256 sim GEMM, pipelined frags --------
// Swapped operands (round-4): output ROW axis = j (z2 row, reduction axis,
// register-indexed), COL axis = i (z1 row, lane-fixed).
// Round-5: register-fragment software pipeline — each phase issues ds_reads
// for the NEXT phase's fragments; MFMAs consume already-resident registers.
// One barrier per K-tile, counted vmcnt(2), full K-loop unroll.
__global__ __launch_bounds__(THREADS, 2) void fused_sim_kernel(
    const unsigned short* __restrict__ A,   // z1n bf16 bits [8192][512]
    const unsigned short* __restrict__ B,   // z2n bf16 bits [8192][512]
    const int* __restrict__ ids,
    float* __restrict__ partial)            // [3][NCB][N_ROWS]
{
    __shared__ unsigned short As[NBUF][TSZ];   // 64 KB
    __shared__ unsigned short Bs[NBUF][TSZ];   // 64 KB
    __shared__ int   idr[BM], idc[BM];         // 2 KB
    __shared__ float red[2][3][BM];            // 6 KB

    const int tid  = threadIdx.x;
    const int lane = tid & 63;
    const int wid  = tid >> 6;
    const int wr   = wid >> 2;                 // 0..1  (j half: 128 B-rows)
    const int wc   = wid & 3;                  // 0..3  (i quarter: 64 A-rows)

    // 2D XCD chunking: each XCD owns a 4-wide bx stripe; by sweeps inside.
    const int flat = blockIdx.x;
    const int xcd  = flat & 7;
    const int sidx = flat >> 3;                // 0..127
    const int bx   = xcd * 4 + (sidx & 3);     // 0..31  (j block)
    const int by   = sidx >> 2;                // 0..31  (i block)
    const int brow = by * BM;
    const int bcol = bx * BM;

    if (tid < BM)           idr[tid]        = ids[brow + tid];
    else if (tid < 2 * BM)  idc[tid - BM]   = ids[bcol + (tid - BM)];

    // staging geometry: thread -> (row-in-half sr = tid>>2, slot sc8 = tid&3)
    // LDS slot (row, c8) holds global column-group c8 ^ ((row>>1)&3)
    const int sr  = tid >> 2;                  // 0..127
    const int sc8 = tid & 3;                   // 0..3
    const int scg = sc8 ^ ((sr >> 1) & 3);     // pre-swizzled source group

    auto stageA = [&](int buf, int k0) {
#pragma unroll
        for (int h = 0; h < 2; ++h) {
            int row = h * 128 + sr;
            gload_lds16(A + (size_t)(brow + row) * DIM + k0 + scg * 8,
                        &As[buf][row * BK + sc8 * 8]);
        }
    };
    auto stageB = [&](int buf, int k0) {
#pragma unroll
        for (int h = 0; h < 2; ++h) {
            int row = h * 128 + sr;
            gload_lds16(B + (size_t)(bcol + row) * DIM + k0 + scg * 8,
                        &Bs[buf][row * BK + sc8 * 8]);
        }
    };

    const int fr = lane & 15;                  // frag row-in-16 / D col (i)
    const int fc = lane >> 4;                  // frag k-group / D row grp (j)

    auto ldB = [&](int buf, int m) -> bf16x8 { // 8 frags: wave's 128 j-rows
        int row = wr * 128 + m * 16 + fr;
        int cs  = fc ^ ((row >> 1) & 3);
        return *(const bf16x8*)&Bs[buf][row * BK + cs * 8];
    };
    auto ldA = [&](int buf, int n) -> bf16x8 { // 4 frags: wave's 64 i-rows
        int row = wc * 64 + n * 16 + fr;
        int cs  = fc ^ ((row >> 1) & 3);
        return *(const bf16x8*)&As[buf][row * BK + cs * 8];
    };

    f32x4 acc[8][4];
#pragma unroll
    for (int m = 0; m < 8; ++m)
#pragma unroll
        for (int n = 0; n < 4; ++n) acc[m][n] = (f32x4)0.f;

    bf16x8 cb[8], ca[4], nb[4], na[4];

    // prologue: stage tiles 0 and 1 (4 per-thread loads each)
    stageA(0, 0);      stageB(0, 0);
    stageA(1, BK);     stageB(1, BK);
    WAITL0();                       // drain idr/idc ds_writes before BAR
    WAITV(4);                       // tile 0 landed (tile 1's 4 in flight)
    BAR();
    // initial fragment reads for tile 0, phase alpha
    cb[0] = ldB(0, 0); cb[1] = ldB(0, 1); cb[2] = ldB(0, 2); cb[3] = ldB(0, 3);
    ca[0] = ldA(0, 0); ca[1] = ldA(0, 1); ca[2] = ldA(0, 2); ca[3] = ldA(0, 3);

#pragma unroll
    for (int t = 0; t < NT; ++t) {
        const int cur = t & 3;
        const int nxt = (t + 1) & 3;
        const int nb2 = (t + 2) & 3;
        const int k2  = (t + 2) * BK;

        // ---- phase alpha: read b4-7[t]; MFMA b0-3[t] x a0-3[t] ----
        cb[4] = ldB(cur, 4); cb[5] = ldB(cur, 5); cb[6] = ldB(cur, 6); cb[7] = ldB(cur, 7);
        if (t + 2 < NT) stageA(nb2, k2);
        __builtin_amdgcn_s_setprio(1);
        acc[0][0] = __builtin_amdgcn_mfma_f32_16x16x32_bf16(cb[0], ca[0], acc[0][0], 0, 0, 0);
        acc[0][1] = __builtin_amdgcn_mfma_f32_16x16x32_bf16(cb[0], ca[1], acc[0][1], 0, 0, 0);
        acc[0][2] = __builtin_amdgcn_mfma_f32_16x16x32_bf16(cb[0], ca[2], acc[0][2], 0, 0, 0);
        acc[0][3] = __builtin_amdgcn_mfma_f32_16x16x32_bf16(cb[0], ca[3], acc[0][3], 0, 0, 0);
        acc[1][0] = __builtin_amdgcn_mfma_f32_16x16x32_bf16(cb[1], ca[0], acc[1][0], 0, 0, 0);
        acc[1][1] = __builtin_amdgcn_mfma_f32_16x16x32_bf16(cb[1], ca[1], acc[1][1], 0, 0, 0);
        acc[1][2] = __builtin_amdgcn_mfma_f32_16x16x32_bf16(cb[1], ca[2], acc[1][2], 0, 0, 0);
        acc[1][3] = __builtin_amdgcn_mfma_f32_16x16x32_bf16(cb[1], ca[3], acc[1][3], 0, 0, 0);
        acc[2][0] = __builtin_amdgcn_mfma_f32_16x16x32_bf16(cb[2], ca[0], acc[2][0], 0, 0, 0);
        acc[2][1] = __builtin_amdgcn_mfma_f32_16x16x32_bf16(cb[2], ca[1], acc[2][1], 0, 0, 0);
        acc[2][2] = __builtin_amdgcn_mfma_f32_16x16x32_bf16(cb[2], ca[2], acc[2][2], 0, 0, 0);
        acc[2][3] = __builtin_amdgcn_mfma_f32_16x16x32_bf16(cb[2], ca[3], acc[2][3], 0, 0, 0);
        acc[3][0] = __builtin_amdgcn_mfma_f32_16x16x32_bf16(cb[3], ca[0], acc[3][0], 0, 0, 0);
        acc[3][1] = __builtin_amdgcn_mfma_f32_16x16x32_bf16(cb[3], ca[1], acc[3][1], 0, 0, 0);
        acc[3][2] = __builtin_amdgcn_mfma_f32_16x16x32_bf16(cb[3], ca[2], acc[3][2], 0, 0, 0);
        acc[3][3] = __builtin_amdgcn_mfma_f32_16x16x32_bf16(cb[3], ca[3], acc[3][3], 0, 0, 0);
        __builtin_amdgcn_s_setprio(0);

        // ---- phase beta: wait+bar for tile t+1, read its alpha frags,
        //      MFMA b4-7[t] x a0-3[t] ----
        if (t < NT - 2) { WAITV(2); } else { WAITV(0); }
        BAR();
        if (t + 1 < NT) {
            nb[0] = ldB(nxt, 0); nb[1] = ldB(nxt, 1); nb[2] = ldB(nxt, 2); nb[3] = ldB(nxt, 3);
            na[0] = ldA(nxt, 0); na[1] = ldA(nxt, 1); na[2] = ldA(nxt, 2); na[3] = ldA(nxt, 3);
        }
        if (t + 2 < NT) stageB(nb2, k2);
        __builtin_amdgcn_s_setprio(1);
        acc[4][0] = __builtin_amdgcn_mfma_f32_16x16x32_bf16(cb[4], ca[0], acc[4][0], 0, 0, 0);
        acc[4][1] = __builtin_amdgcn_mfma_f32_16x16x32_bf16(cb[4], ca[1], acc[4][1], 0, 0, 0);
        acc[4][2] = __builtin_amdgcn_mfma_f32_16x16x32_bf16(cb[4], ca[2], acc[4][2], 0, 0, 0);
        acc[4][3] = __builtin_amdgcn_mfma_f32_16x16x32_bf16(cb[4], ca[3], acc[4][3], 0, 0, 0);
        acc[5][0] = __builtin_amdgcn_mfma_f32_16x16x32_bf16(cb[5], ca[0], acc[5][0], 0, 0, 0);
        acc[5][1] = __builtin_amdgcn_mfma_f32_16x16x32_bf16(cb[5], ca[1], acc[5][1], 0, 0, 0);
        acc[5][2] = __builtin_amdgcn_mfma_f32_16x16x32_bf16(cb[5], ca[2], acc[5][2], 0, 0, 0);
        acc[5][3] = __builtin_amdgcn_mfma_f32_16x16x32_bf16(cb[5], ca[3], acc[5][3], 0, 0, 0);
        acc[6][0] = __builtin_amdgcn_mfma_f32_16x16x32_bf16(cb[6], ca[0], acc[6][0], 0, 0, 0);
        acc[6][1] = __builtin_amdgcn_mfma_f32_16x16x32_bf16(cb[6], ca[1], acc[6][1], 0, 0, 0);
        acc[6][2] = __builtin_amdgcn_mfma_f32_16x16x32_bf16(cb[6], ca[2], acc[6][2], 0, 0, 0);
        acc[6][3] = __builtin_amdgcn_mfma_f32_16x16x32_bf16(cb[6], ca[3], acc[6][3], 0, 0, 0);
        acc[7][0] = __builtin_amdgcn_mfma_f32_16x16x32_bf16(cb[7], ca[0], acc[7][0], 0, 0, 0);
        acc[7][1] = __builtin_amdgcn_mfma_f32_16x16x32_bf16(cb[7], ca[1], acc[7][1], 0, 0, 0);
        acc[7][2] = __builtin_amdgcn_mfma_f32_16x16x32_bf16(cb[7], ca[2], acc[7][2], 0, 0, 0);
        acc[7][3] = __builtin_amdgcn_mfma_f32_16x16x32_bf16(cb[7], ca[3], acc[7][3], 0, 0, 0);
        __builtin_amdgcn_s_setprio(0);
        if (t + 1 < NT) {
            cb[0] = nb[0]; cb[1] = nb[1]; cb[2] = nb[2]; cb[3] = nb[3];
            ca[0] = na[0]; ca[1] = na[1]; ca[2] = na[2]; ca[3] = na[3];
        }
    }

    // ---- epilogue: per-lane register accumulation over j, 2-hop butterfly
    // D layout: col (i) = lane&15 fixed; row (j) = fc*4 + reg within 16-block.
    const int rg = fc;
    int   rid[4];
    float dp[4], sp[4], qp[4];
#pragma unroll
    for (int ni = 0; ni < 4; ++ni) {
        rid[ni] = idr[wc * 64 + ni * 16 + fr];
        dp[ni] = 0.f; sp[ni] = 0.f; qp[ni] = 0.f;
    }
#pragma unroll
    for (int mj = 0; mj < 8; ++mj) {
#pragma unroll
        for (int r = 0; r < 4; ++r) {
            int j   = wr * 128 + mj * 16 + rg * 4 + r;
            int cid = idc[j];                       // broadcast within rg group
#pragma unroll
            for (int ni = 0; ni < 4; ++ni) {
                float v = acc[mj][ni][r];
                float e = __expf(v * 10.0f - 10.0f);    // exp(sim - 10)
                bool msk = (rid[ni] == cid);
                dp[ni] += e;
                sp[ni] += msk ? e : 0.f;
                qp[ni] += msk ? 0.f : e * e;
            }
        }
    }
#pragma unroll
    for (int ni = 0; ni < 4; ++ni) {
#pragma unroll
        for (int x = 16; x < 64; x <<= 1) {
            dp[ni] += __shfl_xor(dp[ni], x);
            sp[ni] += __shfl_xor(sp[ni], x);
            qp[ni] += __shfl_xor(qp[ni], x);
        }
    }
    // lane (rg, fr) stores ni = rg's values (static select, no runtime index)
    {
        float dv = (rg == 0) ? dp[0] : (rg == 1) ? dp[1] : (rg == 2) ? dp[2] : dp[3];
        float sv = (rg == 0) ? sp[0] : (rg == 1) ? sp[1] : (rg == 2) ? sp[2] : sp[3];
        float qv = (rg == 0) ? qp[0] : (rg == 1) ? qp[1] : (rg == 2) ? qp[2] : qp[3];
        int i = wc * 64 + rg * 16 + fr;
        red[wr][0][i] = dv;
        red[wr][1][i] = sv;
        red[wr][2][i] = qv;
    }
    __syncthreads();
    if (tid < BM) {
#pragma unroll
        for (int s = 0; s < 3; ++s) {
            float v = red[0][s][tid] + red[1][s][tid];
            partial[((size_t)s * NCB + bx) * N_ROWS + brow + tid] = v;
        }
    }
}

// ---------------- Kernel 3: per-row loss, per-block sums ----------------
__global__ __launch_bounds__(256) void reduce_kernel(
    const float* __restrict__ partial, float* __restrict__ blocksum)
{
    int row = blockIdx.x * 256 + threadIdx.x;
    float den = 0.f, sm = 0.f, sq = 0.f;
#pragma unroll 4
    for (int cb = 0; cb < NCB; ++cb) {
        den += partial[((size_t)0 * NCB + cb) * N_ROWS + row];
        sm  += partial[((size_t)1 * NCB + cb) * N_ROWS + row];
        sq  += partial[((size_t)2 * NCB + cb) * N_ROWS + row];
    }
    float num  = sm + sq / den;
    float loss = -logf(num / (den + 1e-8f) + 1e-8f);
#pragma unroll
    for (int x = 1; x < 64; x <<= 1) loss += __shfl_xor(loss, x);
    __shared__ float p[4];
    if ((threadIdx.x & 63) == 0) p[threadIdx.x >> 6] = loss;
    __syncthreads();
    if (threadIdx.x == 0) blocksum[blockIdx.x] = p[0] + p[1] + p[2] + p[3];
}

__global__ void final_kernel(const float* __restrict__ blocksum, float* __restrict__ out)
{
    float v = (threadIdx.x < 32) ? blocksum[threadIdx.x] : 0.f;
#pragma unroll
    for (int x = 1; x < 64; x <<= 1) v += __shfl_xor(v, x);
    if (threadIdx.x == 0) out[0] = v * (1.0f / (float)N_ROWS);
}

extern "C" void kernel_launch(void* const* d_in, const int* in_sizes, int n_in,
                              void* d_out, int out_size, void* d_ws, size_t ws_size,
                              hipStream_t stream) {
    const float* z1  = (const float*)d_in[0];
    const float* z2  = (const float*)d_in[1];
    const int*   ids = (const int*)d_in[2];

    char* ws = (char*)d_ws;
    unsigned short* z1n = (unsigned short*)ws;                                   // 8 MB
    unsigned short* z2n = (unsigned short*)(ws + (size_t)N_ROWS * DIM * 2);      // 8 MB
    float* partial  = (float*)(ws + (size_t)N_ROWS * DIM * 4);                   // 3 MB
    float* blocksum = partial + (size_t)3 * NCB * N_ROWS;                        // 128 B

    norm_cast_kernel<<<dim3(4096), dim3(256), 0, stream>>>(z1, z2, z1n, z2n);
    fused_sim_kernel<<<dim3(1024), dim3(THREADS), 0, stream>>>(z1n, z2n, ids, partial);
    reduce_kernel<<<dim3(32), dim3(256), 0, stream>>>(partial, blocksum);
    final_kernel<<<dim3(1), dim3(64), 0, stream>>>(blocksum, (float*)d_out);
}

// Round 6
// 77.527 us; speedup vs baseline: 4.2499x; 1.2912x over previous
//
#include <hip/hip_runtime.h>
#include <stdint.h>

#define N_ROWS  8192
#define DIM     512            // elements = bytes (fp8)
#define BM      256            // tile M = N = 256
#define BK      64             // K-bytes per tile
#define NT      (DIM / BK)     // 8 K-tiles
#define NBUF    4              // LDS ring buffers
#define TB      (BM * BK)      // 16 KB per tile side
#define NCB     32             // column blocks (8192/256)
#define THREADS 512
#define SCL16   0x7B7B7B7BU    // e8m0 123 = 2^-4 per operand (undoes data x16)

typedef __attribute__((ext_vector_type(16))) float f32x16;
typedef __attribute__((ext_vector_type(8)))  int   i32x8;

#define BAR()    { asm volatile("" ::: "memory"); __builtin_amdgcn_s_barrier(); asm volatile("" ::: "memory"); }
#define WAITV(n) asm volatile("s_waitcnt vmcnt(" #n ")" ::: "memory")
#define WAITL0() asm volatile("s_waitcnt lgkmcnt(0)" ::: "memory")

#define MFMA8(a, b, c) __builtin_amdgcn_mfma_scale_f32_32x32x64_f8f6f4( \
    (a), (b), (c), 0, 0, 0, SCL16, 0, SCL16)

// manual RNE float -> OCP e4m3fn (|f| <= 16 guaranteed; no NaN/inf inputs)
__device__ __forceinline__ unsigned int f2e4m3(float f) {
    unsigned int u = __float_as_uint(f);
    unsigned int s = (u >> 24) & 0x80u;
    float a = fabsf(f);
    if (a < 0.015625f) {                     // subnormal: step 2^-9
        int q = (int)rintf(a * 512.0f);      // 0..8 (8 rolls into min-normal)
        return s | (unsigned int)q;
    }
    unsigned int mag = u & 0x7fffffffu;
    mag += 0x7FFFFu + ((mag >> 20) & 1u);    // RNE into 3-bit mantissa
    return s | ((mag >> 20) - 960u);         // (E-120)<<3 | M3
}

// async global -> LDS, 16 B per lane (lane-linear LDS dest)
__device__ __forceinline__ void gload_lds16(const void* g, void* l) {
    __builtin_amdgcn_global_load_lds(
        (const __attribute__((address_space(1))) unsigned int*)g,
        (__attribute__((address_space(3))) unsigned int*)l,
        16, 0, 0);
}

// ---------------- Kernel 1: L2-normalize rows + cast to fp8 (x16) ----------
__global__ __launch_bounds__(256) void norm_cast_kernel(
    const float* __restrict__ z1, const float* __restrict__ z2,
    unsigned char* __restrict__ o1, unsigned char* __restrict__ o2)
{
    int row  = blockIdx.x * 4 + (threadIdx.x >> 6);
    int lane = threadIdx.x & 63;
    const float* src;
    unsigned char* dst;
    if (row < N_ROWS) { src = z1 + (size_t)row * DIM;            dst = o1 + (size_t)row * DIM; }
    else              { src = z2 + (size_t)(row - N_ROWS) * DIM; dst = o2 + (size_t)(row - N_ROWS) * DIM; }

    const float4* s4 = (const float4*)src + lane * 2;
    float4 a = s4[0], b = s4[1];
    float ss = a.x*a.x + a.y*a.y + a.z*a.z + a.w*a.w
             + b.x*b.x + b.y*b.y + b.z*b.z + b.w*b.w;
#pragma unroll
    for (int x = 1; x < 64; x <<= 1) ss += __shfl_xor(ss, x);
    float inv = 16.0f / fmaxf(sqrtf(ss), 1e-12f);   // x16 into e4m3 normal range

    uint2 o;
    o.x = f2e4m3(a.x*inv) | (f2e4m3(a.y*inv) << 8) | (f2e4m3(a.z*inv) << 16) | (f2e4m3(a.w*inv) << 24);
    o.y = f2e4m3(b.x*inv) | (f2e4m3(b.y*inv) << 8) | (f2e4m3(b.z*inv) << 16) | (f2e4m3(b.w*inv) << 24);
    *(uint2*)(dst + lane * 8) = o;
}

// ---------------- Kernel 2: fused 256x256 MX-fp8 sim GEMM ------------------
// Swapped operands: acc[jb][ib] = mfma(Jfrag, Ifrag): output ROW axis = j
// (z2 row, reduction axis, register-indexed), COL axis = i (z1 row, lane).
// LDS is fragment-linear: [frag-block][lane][32 B] so staging writes and
// ds_read_b128 frag reads are both the canonical lane-linear pattern.
__global__ __launch_bounds__(THREADS, 2) void fused_sim_kernel(
    const unsigned char* __restrict__ A,    // z1 fp8 [8192][512]
    const unsigned char* __restrict__ B,    // z2 fp8 [8192][512]
    const int* __restrict__ ids,
    float* __restrict__ partial)            // [3][NCB][N_ROWS]
{
    __shared__ alignas(128) unsigned char As[NBUF][TB];   // 64 KB
    __shared__ alignas(128) unsigned char Bs[NBUF][TB];   // 64 KB
    __shared__ int   idr[BM], idc[BM];                    // 2 KB
    __shared__ float red[2][3][BM];                       // 6 KB

    const int tid  = threadIdx.x;
    const int lane = tid & 63;
    const int wid  = tid >> 6;
    const int wr   = wid >> 2;                 // 0..1  (j half: 128 rows)
    const int wc   = wid & 3;                  // 0..3  (i quarter: 64 rows)

    // 2D XCD chunking: each XCD owns a 4-wide bx stripe; by sweeps inside.
    const int flat = blockIdx.x;
    const int xcd  = flat & 7;
    const int sidx = flat >> 3;
    const int bx   = xcd * 4 + (sidx & 3);     // 0..31  (j block)
    const int by   = sidx >> 2;                // 0..31  (i block)
    const int brow = by * BM;
    const int bcol = bx * BM;

    if (tid < BM) idr[tid] = ids[brow + tid];
    else          idc[tid - BM] = ids[bcol + (tid - BM)];
    WAITL0();   // drain id ds_writes (and their vmcnt) before staging issues

    // stage one 256x64B tile side: 2 instrs/thread, fragment-linear LDS.
    // seg -> (blk = seg>>7, lane_f = (seg&127)>>1, half = seg&1)
    auto stageA = [&](int buf, int k0) {
#pragma unroll
        for (int g = 0; g < 2; ++g) {
            int seg  = g * 512 + tid;
            int lf   = (seg & 127) >> 1, half = seg & 1;
            int row  = (seg >> 7) * 32 + (lf & 31);
            int kb   = (lf >> 5) * 32 + half * 16;
            gload_lds16(A + (size_t)(brow + row) * DIM + k0 + kb, &As[buf][seg * 16]);
        }
    };
    auto stageB = [&](int buf, int k0) {
#pragma unroll
        for (int g = 0; g < 2; ++g) {
            int seg  = g * 512 + tid;
            int lf   = (seg & 127) >> 1, half = seg & 1;
            int row  = (seg >> 7) * 32 + (lf & 31);
            int kb   = (lf >> 5) * 32 + half * 16;
            gload_lds16(B + (size_t)(bcol + row) * DIM + k0 + kb, &Bs[buf][seg * 16]);
        }
    };

    // fragment reads: lane-linear 32 B (operand layout: row = lane&31,
    // k-bytes = (lane>>5)*32 + 0..31)
    auto ldJ = [&](int buf, int jb) -> i32x8 {
        return *(const i32x8*)&Bs[buf][((wr * 4 + jb) * 64 + lane) * 32];
    };
    auto ldI = [&](int buf, int ib) -> i32x8 {
        return *(const i32x8*)&As[buf][((wc * 2 + ib) * 64 + lane) * 32];
    };

    f32x16 acc[4][2];
#pragma unroll
    for (int m = 0; m < 4; ++m)
#pragma unroll
        for (int n = 0; n < 2; ++n) acc[m][n] = (f32x16)0.f;

    i32x8 jf[2][4], iF[2][2];

    // prologue: stage tiles 0,1 (4 instrs each)
    stageA(0, 0);   stageB(0, 0);
    stageA(1, BK);  stageB(1, BK);
    WAITV(4);                      // tile 0 landed; tile 1's 4 in flight
    BAR();
    jf[0][0] = ldJ(0, 0); jf[0][1] = ldJ(0, 1);
    iF[0][0] = ldI(0, 0); iF[0][1] = ldI(0, 1);

#pragma unroll
    for (int t = 0; t < NT; ++t) {
        const int p   = t & 1, q = p ^ 1;
        const int cur = t & 3;
        const int nb2 = (t + 2) & 3;
        const int k2  = (t + 2) * BK;

        // ---- phase alpha: read j2,j3[t]; MFMA (j0,j1)x(i0,i1) ----
        jf[p][2] = ldJ(cur, 2); jf[p][3] = ldJ(cur, 3);
        if (t + 2 < NT) stageA(nb2, k2);
        __builtin_amdgcn_s_setprio(1);
        acc[0][0] = MFMA8(jf[p][0], iF[p][0], acc[0][0]);
        acc[0][1] = MFMA8(jf[p][0], iF[p][1], acc[0][1]);
        acc[1][0] = MFMA8(jf[p][1], iF[p][0], acc[1][0]);
        acc[1][1] = MFMA8(jf[p][1], iF[p][1], acc[1][1]);
        __builtin_amdgcn_s_setprio(0);

        // ---- phase beta: validate tile t+1, read its front frags,
        //      MFMA (j2,j3)x(i0,i1) ----
        if (t < NT - 2) { WAITV(2); } else { WAITV(0); }
        BAR();
        if (t + 1 < NT) {
            const int nxt = (t + 1) & 3;
            jf[q][0] = ldJ(nxt, 0); jf[q][1] = ldJ(nxt, 1);
            iF[q][0] = ldI(nxt, 0); iF[q][1] = ldI(nxt, 1);
        }
        if (t + 2 < NT) stageB(nb2, k2);
        __builtin_amdgcn_s_setprio(1);
        acc[2][0] = MFMA8(jf[p][2], iF[p][0], acc[2][0]);
        acc[2][1] = MFMA8(jf[p][2], iF[p][1], acc[2][1]);
        acc[3][0] = MFMA8(jf[p][3], iF[p][0], acc[3][0]);
        acc[3][1] = MFMA8(jf[p][3], iF[p][1], acc[3][1]);
        __builtin_amdgcn_s_setprio(0);
    }

    // ---- epilogue: 32x32 C/D layout: col(i)=lane&31, row(j)=(reg&3)+8*(reg>>2)+4*(lane>>5)
    const int li = lane & 31, lh = lane >> 5;
    const int rid0 = idr[wc * 64 + li];
    const int rid1 = idr[wc * 64 + 32 + li];
    float dp0 = 0.f, sp0 = 0.f, qp0 = 0.f, dp1 = 0.f, sp1 = 0.f, qp1 = 0.f;
#pragma unroll
    for (int jb = 0; jb < 4; ++jb) {
#pragma unroll
        for (int reg = 0; reg < 16; ++reg) {
            int j   = wr * 128 + jb * 32 + (reg & 3) + 8 * (reg >> 2) + 4 * lh;
            int cid = idc[j];
            float v0 = acc[jb][0][reg], v1 = acc[jb][1][reg];
            float e0 = __expf(v0 * 10.0f - 10.0f);   // exp(sim - 10)
            float e1 = __expf(v1 * 10.0f - 10.0f);
            dp0 += e0; dp1 += e1;
            sp0 += (rid0 == cid) ? e0 : 0.f;  qp0 += (rid0 == cid) ? 0.f : e0 * e0;
            sp1 += (rid1 == cid) ? e1 : 0.f;  qp1 += (rid1 == cid) ? 0.f : e1 * e1;
        }
    }
    dp0 += __shfl_xor(dp0, 32); sp0 += __shfl_xor(sp0, 32); qp0 += __shfl_xor(qp0, 32);
    dp1 += __shfl_xor(dp1, 32); sp1 += __shfl_xor(sp1, 32); qp1 += __shfl_xor(qp1, 32);
    if (lane < 32) {
        red[wr][0][wc * 64 + li]      = dp0;
        red[wr][1][wc * 64 + li]      = sp0;
        red[wr][2][wc * 64 + li]      = qp0;
        red[wr][0][wc * 64 + 32 + li] = dp1;
        red[wr][1][wc * 64 + 32 + li] = sp1;
        red[wr][2][wc * 64 + 32 + li] = qp1;
    }
    __syncthreads();
    if (tid < BM) {
#pragma unroll
        for (int s = 0; s < 3; ++s) {
            float v = red[0][s][tid] + red[1][s][tid];
            partial[((size_t)s * NCB + bx) * N_ROWS + brow + tid] = v;
        }
    }
}

// ---------------- Kernel 3: per-row loss, per-block sums ----------------
__global__ __launch_bounds__(256) void reduce_kernel(
    const float* __restrict__ partial, float* __restrict__ blocksum)
{
    int row = blockIdx.x * 256 + threadIdx.x;
    float den = 0.f, sm = 0.f, sq = 0.f;
#pragma unroll 4
    for (int cb = 0; cb < NCB; ++cb) {
        den += partial[((size_t)0 * NCB + cb) * N_ROWS + row];
        sm  += partial[((size_t)1 * NCB + cb) * N_ROWS + row];
        sq  += partial[((size_t)2 * NCB + cb) * N_ROWS + row];
    }
    float num  = sm + sq / den;
    float loss = -logf(num / (den + 1e-8f) + 1e-8f);
#pragma unroll
    for (int x = 1; x < 64; x <<= 1) loss += __shfl_xor(loss, x);
    __shared__ float p[4];
    if ((threadIdx.x & 63) == 0) p[threadIdx.x >> 6] = loss;
    __syncthreads();
    if (threadIdx.x == 0) blocksum[blockIdx.x] = p[0] + p[1] + p[2] + p[3];
}

__global__ void final_kernel(const float* __restrict__ blocksum, float* __restrict__ out)
{
    float v = (threadIdx.x < 32) ? blocksum[threadIdx.x] : 0.f;
#pragma unroll
    for (int x = 1; x < 64; x <<= 1) v += __shfl_xor(v, x);
    if (threadIdx.x == 0) out[0] = v * (1.0f / (float)N_ROWS);
}

extern "C" void kernel_launch(void* const* d_in, const int* in_sizes, int n_in,
                              void* d_out, int out_size, void* d_ws, size_t ws_size,
                              hipStream_t stream) {
    const float* z1  = (const float*)d_in[0];
    const float* z2  = (const float*)d_in[1];
    const int*   ids = (const int*)d_in[2];

    char* ws = (char*)d_ws;
    unsigned char* z1q = (unsigned char*)ws;                                 // 4 MB
    unsigned char* z2q = (unsigned char*)(ws + (size_t)N_ROWS * DIM);        // 4 MB
    float* partial  = (float*)(ws + (size_t)2 * N_ROWS * DIM);               // 3 MB
    float* blocksum = partial + (size_t)3 * NCB * N_ROWS;                    // 128 B

    norm_cast_kernel<<<dim3(4096), dim3(256), 0, stream>>>(z1, z2, z1q, z2q);
    fused_sim_kernel<<<dim3(1024), dim3(THREADS), 0, stream>>>(z1q, z2q, ids, partial);
    reduce_kernel<<<dim3(32), dim3(256), 0, stream>>>(partial, blocksum);
    final_kernel<<<dim3(1), dim3(64), 0, stream>>>(blocksum, (float*)d_out);
}